// Round 9
// baseline (264.463 us; speedup 1.0000x reference)
//
#include <hip/hip_runtime.h>
#include <math.h>

// Problem constants: B=4, NF=64, H=W=128, K=9
// d_in order: nbr, ref, w1, b1, w2, b2, w3, b3, w_off, b_off, w_dcn, b_dcn
// d_out: feat [4,64,128,128] | offset [4,18,128,128] | mask [4,9,128,128]

typedef _Float16 h8 __attribute__((ext_vector_type(8)));  // 8 f16 (4 VGPRs)
typedef _Float16 h4 __attribute__((ext_vector_type(4)));  // 4 f16 (2 VGPRs)
typedef _Float16 h2 __attribute__((ext_vector_type(2)));  // packed f16 pair
typedef float f4 __attribute__((ext_vector_type(4)));     // 4 fp32 acc

// ================ merged setup: weight prep + border zero + input prep ================
// roles by blockIdx: [0,792) wprep, [792,1050) border zero, [1050,3098) NCHW->padded NHWC f16
__global__ __launch_bounds__(256) void setup_kernel(
    const float* __restrict__ nbr, const float* __restrict__ refp,
    const float* __restrict__ w1, const float* __restrict__ w2,
    const float* __restrict__ w3, const float* __restrict__ w_off,
    const float* __restrict__ w_dcn,
    _Float16* __restrict__ X1, _Float16* __restrict__ X2,
    _Float16* __restrict__ B64, _Float16* __restrict__ C64,
    _Float16* __restrict__ wF1, _Float16* __restrict__ wF2,
    _Float16* __restrict__ wF3, _Float16* __restrict__ wFo,
    _Float16* __restrict__ wFd) {
  __shared__ float t[64 * 65];
  int bid = blockIdx.x;
  int tid = threadIdx.x;
  if (bid < 792) {
    // ---- weight prep (f16)
    int i = bid * 256 + tid;
    if (i < 73728) {                       // w1: global chunk 0..3 (128 IC)
      int j = i;
      int icw = j & 31; int t1 = j >> 5; int oc = t1 & 63; int t2 = t1 >> 6;
      int ch = t2 & 3; int tap = t2 >> 2; int ic = ch * 32 + icw;
      wF1[j] = (_Float16)w1[(oc * 128 + ic) * 9 + tap];
    } else if (i < 110592) {               // w2
      int j = i - 73728;
      int icw = j & 31; int t1 = j >> 5; int oc = t1 & 63; int t2 = t1 >> 6;
      int ch = t2 & 1; int tap = t2 >> 1; int ic = ch * 32 + icw;
      wF2[j] = (_Float16)w2[(oc * 64 + ic) * 9 + tap];
    } else if (i < 147456) {               // w3
      int j = i - 110592;
      int icw = j & 31; int t1 = j >> 5; int oc = t1 & 63; int t2 = t1 >> 6;
      int ch = t2 & 1; int tap = t2 >> 1; int ic = ch * 32 + icw;
      wF3[j] = (_Float16)w3[(oc * 64 + ic) * 9 + tap];
    } else if (i < 165888) {               // w_off padded to 32 oc
      int j = i - 147456;
      int icw = j & 31; int t1 = j >> 5; int oc = t1 & 31; int t2 = t1 >> 5;
      int ch = t2 & 1; int tap = t2 >> 1; int ic = ch * 32 + icw;
      float v = (oc < 27) ? w_off[(oc * 64 + ic) * 9 + tap] : 0.f;
      wFo[j] = (_Float16)v;
    } else if (i < 202752) {               // w_dcn -> [oc][tap*64+c]
      int j = i - 165888;
      int oc = j / 576; int r = j - oc * 576; int tap = r >> 6; int c = r & 63;
      wFd[j] = (_Float16)w_dcn[(oc * 64 + c) * 9 + tap];
    }
    return;
  }
  if (bid < 1050) {
    // ---- zero pad borders of X1, X2, B64, C64 (all CH=64)
    int i = (bid - 792) * 256 + tid;       // 66048 = 4 buf * 4 b * 516 px * 8 chunks
    int bufi = i / 16512;
    int j = i - bufi * 16512;
    int b = j / 4128;
    int r = j - b * 4128;
    int p = r >> 3; int cg = r & 7;
    int row, col;
    if (p < 130)      { row = 0;   col = p; }
    else if (p < 260) { row = 129; col = p - 130; }
    else if (p < 388) { row = 1 + (p - 260); col = 0; }
    else              { row = 1 + (p - 388); col = 129; }
    _Float16* dst = (bufi == 0) ? X1 : (bufi == 1) ? X2 : (bufi == 2) ? B64 : C64;
    uint4 z; z.x = z.y = z.z = z.w = 0u;
    *(uint4*)(dst + ((size_t)(b * 130 + row) * 130 + col) * 64 + cg * 8) = z;
    return;
  }
  // ---- input prep: fp32 NCHW -> padded NHWC f16 (64-px half-rows)
  int j = bid - 1050;                      // 2048 = 2 src * 4 b * 128 y * 2 half
  int half = j & 1;
  int y = (j >> 1) & 127;
  int b = (j >> 8) & 3;
  int src = j >> 10;
  const float* sp = src ? refp : nbr;
  _Float16* dst = src ? X2 : X1;
  for (int l = tid; l < 64 * 64; l += 256) {
    int c = l >> 6, gx = l & 63;
    t[c * 65 + gx] = sp[(((size_t)b * 64 + c) << 14) + (y << 7) + half * 64 + gx];
  }
  __syncthreads();
  unsigned* dstU = (unsigned*)dst;
  for (int l = tid; l < 64 * 32; l += 256) {
    int pxl = l >> 5, c2 = l & 31;
    union { _Float16 h[2]; unsigned u; } pk;
    pk.h[0] = (_Float16)t[(2 * c2) * 65 + pxl];
    pk.h[1] = (_Float16)t[(2 * c2 + 1) * 65 + pxl];
    dstU[((size_t)(b * 130 + y + 1) * 130 + 1 + half * 64 + pxl) * 32 + c2] = pk.u;
  }
}

// ================ f16 MFMA conv3x3 + bias + lrelu -> padded NHWC f16 ================
// All inputs are padded NHWC f16 [B][130][130][64]; conv1 reads two (concat via SPLIT).
// W: f16 slices [(tap*NCH+c)*64+oc][32].
// mfma_f32_16x16x32_f16 (lane L, lm=L&15, lq=L>>4):
//   a[j]=A[m=lm][k=lq*8+j]  b[j]=B[k=lq*8+j][n=lm]  d[r]=D[row=lq*4+r][col=lm]
template <int NCH, bool SPLIT>
__global__ __launch_bounds__(256, 4) void conv3x3_f16_kernel(
    const _Float16* __restrict__ X1, const _Float16* __restrict__ X2,
    const _Float16* __restrict__ W, const float* __restrict__ bias,
    _Float16* __restrict__ outP) {
  int tid = threadIdx.x;
  int wv = tid >> 6, L = tid & 63;
  int lm = L & 15, lq = L >> 4;
  int bid = blockIdx.x;                 // 512 = 8 xcd * 16 ystrip * 4 b
  int xcd = bid & 7, j = bid >> 3;
  int y = (xcd << 4) | (j & 15);
  int b = j >> 4;
  int px0 = wv * 32;

  f4 acc[4][2];
#pragma unroll
  for (int i = 0; i < 4; ++i)
#pragma unroll
    for (int n = 0; n < 2; ++n) acc[i][n] = (f4)0.f;

  for (int c = 0; c < NCH; ++c) {
    const _Float16* src = (SPLIT && c >= 2) ? X2 : X1;
    int cl = SPLIT ? (c & 1) : c;
#pragma unroll
    for (int tap = 0; tap < 9; ++tap) {
      const int dy = tap / 3 - 1, dx = tap % 3 - 1;
      const _Float16* xb = src + ((size_t)((b * 130 + (y + 1 + dy)) * 130) + (1 + dx) + px0) * 64
                               + cl * 32 + lq * 8;
      h8 b0 = *(const h8*)(xb + lm * 64);
      h8 b1 = *(const h8*)(xb + (16 + lm) * 64);
      const _Float16* wp = W + (size_t)((tap * NCH + c) * 64) * 32 + lm * 32 + lq * 8;
      h8 a0 = *(const h8*)(wp);
      h8 a1 = *(const h8*)(wp + 512);
      h8 a2 = *(const h8*)(wp + 1024);
      h8 a3 = *(const h8*)(wp + 1536);
      acc[0][0] = __builtin_amdgcn_mfma_f32_16x16x32_f16(a0, b0, acc[0][0], 0, 0, 0);
      acc[1][0] = __builtin_amdgcn_mfma_f32_16x16x32_f16(a1, b0, acc[1][0], 0, 0, 0);
      acc[2][0] = __builtin_amdgcn_mfma_f32_16x16x32_f16(a2, b0, acc[2][0], 0, 0, 0);
      acc[3][0] = __builtin_amdgcn_mfma_f32_16x16x32_f16(a3, b0, acc[3][0], 0, 0, 0);
      acc[0][1] = __builtin_amdgcn_mfma_f32_16x16x32_f16(a0, b1, acc[0][1], 0, 0, 0);
      acc[1][1] = __builtin_amdgcn_mfma_f32_16x16x32_f16(a1, b1, acc[1][1], 0, 0, 0);
      acc[2][1] = __builtin_amdgcn_mfma_f32_16x16x32_f16(a2, b1, acc[2][1], 0, 0, 0);
      acc[3][1] = __builtin_amdgcn_mfma_f32_16x16x32_f16(a3, b1, acc[3][1], 0, 0, 0);
    }
  }
  // epilogue: bias + lrelu, pack 4 consecutive oc -> 8 B store, padded NHWC f16
  const size_t obase = ((size_t)(b * 130 + (y + 1)) * 130 + 1) * 64;
#pragma unroll
  for (int mt = 0; mt < 4; ++mt)
#pragma unroll
    for (int nt = 0; nt < 2; ++nt) {
      int px = px0 + nt * 16 + lm;
      h4 pk;
#pragma unroll
      for (int r = 0; r < 4; ++r) {
        int oc = mt * 16 + lq * 4 + r;
        float v = acc[mt][nt][r] + bias[oc];
        v = (v >= 0.f) ? v : 0.1f * v;
        pk[r] = (_Float16)v;
      }
      *(h4*)(outP + obase + (size_t)px * 64 + mt * 16 + lq * 4) = pk;
    }
}

// ================ f16 MFMA conv_off: 64 -> 27(pad 32), fused 15*tanh / sigmoid ========
__global__ __launch_bounds__(256, 4) void conv_off_f16_kernel(
    const _Float16* __restrict__ X, const _Float16* __restrict__ W,
    const float* __restrict__ bias, float* __restrict__ off_out,
    float* __restrict__ mask_out) {
  int tid = threadIdx.x;
  int wv = tid >> 6, L = tid & 63;
  int lm = L & 15, lq = L >> 4;
  int bid = blockIdx.x;
  int xcd = bid & 7, j = bid >> 3;
  int y = (xcd << 4) | (j & 15);
  int b = j >> 4;
  int px0 = wv * 32;

  f4 acc[2][2];
#pragma unroll
  for (int i = 0; i < 2; ++i)
#pragma unroll
    for (int n = 0; n < 2; ++n) acc[i][n] = (f4)0.f;

  for (int c = 0; c < 2; ++c) {
#pragma unroll
    for (int tap = 0; tap < 9; ++tap) {
      const int dy = tap / 3 - 1, dx = tap % 3 - 1;
      const _Float16* xb = X + ((size_t)((b * 130 + (y + 1 + dy)) * 130) + (1 + dx) + px0) * 64
                             + c * 32 + lq * 8;
      h8 b0 = *(const h8*)(xb + lm * 64);
      h8 b1 = *(const h8*)(xb + (16 + lm) * 64);
      const _Float16* wp = W + (size_t)((tap * 2 + c) * 32 + lm) * 32 + lq * 8;
      h8 a0 = *(const h8*)(wp);
      h8 a1 = *(const h8*)(wp + 512);
      acc[0][0] = __builtin_amdgcn_mfma_f32_16x16x32_f16(a0, b0, acc[0][0], 0, 0, 0);
      acc[1][0] = __builtin_amdgcn_mfma_f32_16x16x32_f16(a1, b0, acc[1][0], 0, 0, 0);
      acc[0][1] = __builtin_amdgcn_mfma_f32_16x16x32_f16(a0, b1, acc[0][1], 0, 0, 0);
      acc[1][1] = __builtin_amdgcn_mfma_f32_16x16x32_f16(a1, b1, acc[1][1], 0, 0, 0);
    }
  }
#pragma unroll
  for (int mt = 0; mt < 2; ++mt)
#pragma unroll
    for (int nt = 0; nt < 2; ++nt) {
      int px = px0 + nt * 16 + lm;
      int hw = (y << 7) + px;
#pragma unroll
      for (int r = 0; r < 4; ++r) {
        int oc = mt * 16 + lq * 4 + r;
        if (oc < 18) {
          float v = acc[mt][nt][r] + bias[oc];
          off_out[((b * 18 + oc) << 14) + hw] = 15.f * tanhf(v);
        } else if (oc < 27) {
          float v = acc[mt][nt][r] + bias[oc];
          mask_out[((b * 9 + (oc - 18)) << 14) + hw] = 1.f / (1.f + expf(-v));
        }
      }
    }
}

// ================ DCN: direct-to-fragment bilinear sample + MFMA. No LDS, no barriers.
// Xp: PADDED NHWC f16 [B][130][130][64] (= X1); wD: f16 [oc][tap*64+c] (K=576).
// Wave tile M=64(oc) x N=16(px); lane(lm,lq): B-frag b[j]=sample(px=lm, ch=ks*32+lq*8+j)
// gathered directly as one h8 load per corner (the fragment layout IS 8 contiguous
// channels of one pixel). A-frag from wD at lm*576 (proven addressing). 4 MFMAs/(tap,ks).
__global__ __launch_bounds__(256, 4) void dcn_mfma_kernel(
    const _Float16* __restrict__ Xp, const float* __restrict__ off,
    const float* __restrict__ msk, const _Float16* __restrict__ wD,
    const float* __restrict__ bias, float* __restrict__ out) {
  int tid = threadIdx.x;
  int wv = tid >> 6, L = tid & 63;
  int lm = L & 15, lq = L >> 4;
  int g = blockIdx.x;                 // 1024 = 4 b * 128 y * 2 half
  int half = g & 1;
  int y = (g >> 1) & 127;
  int b = g >> 8;
  int px = half * 64 + wv * 16 + lm;  // this lane's pixel column
  int hw = (y << 7) + px;
  int rb = b * 130;

  f4 acc[4];
#pragma unroll
  for (int i = 0; i < 4; ++i) acc[i] = (f4)0.f;

#pragma unroll
  for (int tap = 0; tap < 9; ++tap) {
    const int kr = tap / 3, kc = tap % 3;
    float oy = off[((b * 18 + 2 * tap) << 14) + hw];
    float ox = off[((b * 18 + 2 * tap + 1) << 14) + hw];
    float m = msk[((b * 9 + tap) << 14) + hw];
    float py = (float)(y + kr - 1) + oy;
    float pxf = (float)(px + kc - 1) + ox;
    float fy = floorf(py), fx = floorf(pxf);
    float wy = py - fy, wx = pxf - fx;
    int y0 = (int)fy, x0 = (int)fx;
    int y1 = y0 + 1, x1 = x0 + 1;
    float vy0 = ((unsigned)y0 < 128u) ? 1.f : 0.f;
    float vy1 = ((unsigned)y1 < 128u) ? 1.f : 0.f;
    float vx0 = ((unsigned)x0 < 128u) ? 1.f : 0.f;
    float vx1 = ((unsigned)x1 < 128u) ? 1.f : 0.f;
    float ey = 1.f - wy, ex = 1.f - wx;
    _Float16 w00 = (_Float16)(ey * ex * m * vy0 * vx0);
    _Float16 w01 = (_Float16)(ey * wx * m * vy0 * vx1);
    _Float16 w10 = (_Float16)(wy * ex * m * vy1 * vx0);
    _Float16 w11 = (_Float16)(wy * wx * m * vy1 * vx1);
    h2 W00 = {w00, w00}, W01 = {w01, w01}, W10 = {w10, w10}, W11 = {w11, w11};
    int y0c = min(max(y0, 0), 127) + 1, y1c = min(max(y1, 0), 127) + 1;
    int x0c = min(max(x0, 0), 127) + 1, x1c = min(max(x1, 0), 127) + 1;
    const size_t b00 = (size_t)((rb + y0c) * 130 + x0c) << 6;
    const size_t b01 = (size_t)((rb + y0c) * 130 + x1c) << 6;
    const size_t b10 = (size_t)((rb + y1c) * 130 + x0c) << 6;
    const size_t b11 = (size_t)((rb + y1c) * 130 + x1c) << 6;
#pragma unroll
    for (int ks = 0; ks < 2; ++ks) {
      const int co = ks * 32 + lq * 8;
      h8 v00 = *(const h8*)(Xp + b00 + co);
      h8 v01 = *(const h8*)(Xp + b01 + co);
      h8 v10 = *(const h8*)(Xp + b10 + co);
      h8 v11 = *(const h8*)(Xp + b11 + co);
      h8 bv;
#pragma unroll
      for (int j2 = 0; j2 < 4; ++j2) {
        h2 a = {v00[2 * j2], v00[2 * j2 + 1]};
        h2 bb = {v01[2 * j2], v01[2 * j2 + 1]};
        h2 cc = {v10[2 * j2], v10[2 * j2 + 1]};
        h2 dd = {v11[2 * j2], v11[2 * j2 + 1]};
        h2 r = a * W00;
        r += bb * W01;
        r += cc * W10;
        r += dd * W11;
        bv[2 * j2] = r[0];
        bv[2 * j2 + 1] = r[1];
      }
      const _Float16* wp = wD + (size_t)lm * 576 + tap * 64 + co;
      h8 a0 = *(const h8*)(wp);
      h8 a1 = *(const h8*)(wp + 16 * 576);
      h8 a2 = *(const h8*)(wp + 32 * 576);
      h8 a3 = *(const h8*)(wp + 48 * 576);
      acc[0] = __builtin_amdgcn_mfma_f32_16x16x32_f16(a0, bv, acc[0], 0, 0, 0);
      acc[1] = __builtin_amdgcn_mfma_f32_16x16x32_f16(a1, bv, acc[1], 0, 0, 0);
      acc[2] = __builtin_amdgcn_mfma_f32_16x16x32_f16(a2, bv, acc[2], 0, 0, 0);
      acc[3] = __builtin_amdgcn_mfma_f32_16x16x32_f16(a3, bv, acc[3], 0, 0, 0);
    }
  }
  // epilogue: bias + lrelu, fp32 NCHW (lane col = px)
#pragma unroll
  for (int mt = 0; mt < 4; ++mt)
#pragma unroll
    for (int r = 0; r < 4; ++r) {
      int oc = mt * 16 + lq * 4 + r;
      float v = acc[mt][r] + bias[oc];
      v = (v >= 0.f) ? v : 0.1f * v;
      out[(((b << 6) + oc) << 14) + (y << 7) + px] = v;
    }
}

extern "C" void kernel_launch(void* const* d_in, const int* in_sizes, int n_in,
                              void* d_out, int out_size, void* d_ws, size_t ws_size,
                              hipStream_t stream) {
  const float* nbr   = (const float*)d_in[0];
  const float* refp  = (const float*)d_in[1];
  const float* w1    = (const float*)d_in[2];
  const float* b1    = (const float*)d_in[3];
  const float* w2    = (const float*)d_in[4];
  const float* b2    = (const float*)d_in[5];
  const float* w3    = (const float*)d_in[6];
  const float* b3    = (const float*)d_in[7];
  const float* w_off = (const float*)d_in[8];
  const float* b_off = (const float*)d_in[9];
  const float* w_dcn = (const float*)d_in[10];
  const float* b_dcn = (const float*)d_in[11];

  float* outp = (float*)d_out;
  float* feat = outp;                       // 4*64*16384
  float* offp = outp + 4194304;             // 4*18*16384
  float* mskp = outp + 4194304 + 1179648;   // 4*9*16384

  // ws layout: four padded NHWC f16 buffers [4][130][130][64] + f16 weights (~33.4 MiB)
  char* ws = (char*)d_ws;
  const size_t PB = 8652800;                // bytes per padded buffer
  _Float16* X1  = (_Float16*)ws;            // nbr padded (conv1 in + DCN sample src)
  _Float16* X2  = (_Float16*)(ws + PB);     // ref padded
  _Float16* B64 = (_Float16*)(ws + 2 * PB); // conv1 out / conv3 out
  _Float16* C64 = (_Float16*)(ws + 3 * PB); // conv2 out
  char* p = ws + 4 * PB;
  _Float16* wF1 = (_Float16*)p;  p += (size_t)73728 * 2;
  _Float16* wF2 = (_Float16*)p;  p += (size_t)36864 * 2;
  _Float16* wF3 = (_Float16*)p;  p += (size_t)36864 * 2;
  _Float16* wFo = (_Float16*)p;  p += (size_t)18432 * 2;
  _Float16* wFd = (_Float16*)p;

  // 6 dispatches total
  setup_kernel<<<dim3(3098), 256, 0, stream>>>(nbr, refp, w1, w2, w3, w_off, w_dcn,
                                               X1, X2, B64, C64, wF1, wF2, wF3, wFo, wFd);
  conv3x3_f16_kernel<4, true><<<dim3(512), 256, 0, stream>>>(X1, X2, wF1, b1, B64);
  conv3x3_f16_kernel<2, false><<<dim3(512), 256, 0, stream>>>(B64, B64, wF2, b2, C64);
  conv3x3_f16_kernel<2, false><<<dim3(512), 256, 0, stream>>>(C64, C64, wF3, b3, B64);
  conv_off_f16_kernel<<<dim3(512), 256, 0, stream>>>(B64, wFo, b_off, offp, mskp);
  dcn_mfma_kernel<<<dim3(1024), 256, 0, stream>>>(X1, offp, mskp, wFd, b_dcn, feat);
}